// Round 7
// baseline (647.110 us; speedup 1.0000x reference)
//
#include <hip/hip_runtime.h>
#include <hip/hip_bf16.h>
#include <cstddef>

// AxialAttention (Music-Transformer skew trick), MFMA bf16, pipelined v5.
// B=8, N=1024, C=512, H=8, d=64.
// logits[r,t] = scale*q[r].k[t] + q[rsel].Erq'[p] + k[rsel].Erk'[p]
//   u=t-r, p=u+N-1, rsel=r+(u>=1)
// S[r]=sum p v; U[r]=sum p Erv[m+r-(N-1)]; W[r]=sum p Erv[m+r+1]
// y[r]=(S+U)/Z; wz[r]=W/Z; out = (y + rowshift(wz)) @ Wo + bo
// MFMA 16x16x32 bf16: A[m=lane&15][k=quad*8+j], B[n=lane&15][k=quad*8+j],
// C/D col=lane&15, row=quad*4+reg.
//
// v5: U/W B-fragments come straight from the 400KB L2-resident padded ervp
// table via a register-carried sliding window (fu0(t+32)=fu1(t)) — EUt/EWt
// LDS rings deleted. LDS ~27KB -> 4 blocks/CU (launch_bounds 256,4).
// proj/out reverted to the R4 versions (R6 prefetch variant regressed).

#define BB 8
#define NN 1024
#define CC 512
#define HH 8
#define DD 64
#define PM 8192
#define EW3 3200  // ervTpad width

typedef unsigned short ushort_t;
typedef unsigned int uint_t;
typedef __bf16 bf16x8 __attribute__((ext_vector_type(8)));
typedef float f32x4 __attribute__((ext_vector_type(4)));
#define MFMA(a, b, c) __builtin_amdgcn_mfma_f32_16x16x32_bf16(a, b, c, 0, 0, 0)

// Barrier that only drains LDS ops: private (register-destined) global loads
// stay outstanding across the barrier. Safe here: all cross-thread data flows
// through LDS (drained by lgkmcnt(0)); global loads are thread-private.
__device__ __forceinline__ void fast_barrier() {
  asm volatile("s_waitcnt lgkmcnt(0)\n\ts_barrier" ::: "memory");
}

__device__ __forceinline__ ushort_t f2bf(float f) {
  union { float f; uint_t u; } v; v.f = f;
  uint_t r = v.u + 0x7FFFu + ((v.u >> 16) & 1u);
  return (ushort_t)(r >> 16);
}
__device__ __forceinline__ float bf2f(ushort_t u) {
  union { uint_t u; float f; } v; v.u = ((uint_t)u) << 16; return v.f;
}
__device__ __forceinline__ float4 ldg4(const float* p) { return *(const float4*)p; }

// ---------------- prep ----------------
__global__ __launch_bounds__(256) void prep_kernel(
    const float* __restrict__ x, const float* __restrict__ Wq,
    const float* __restrict__ Wk, const float* __restrict__ Wv,
    const float* __restrict__ Erq, const float* __restrict__ Erk,
    const float* __restrict__ Erv, const float* __restrict__ Wo,
    ushort_t* __restrict__ xh, ushort_t* __restrict__ xl,
    ushort_t* __restrict__ wt, ushort_t* __restrict__ erqb,
    ushort_t* __restrict__ erkb, ushort_t* __restrict__ ervp,
    ushort_t* __restrict__ woh, ushort_t* __restrict__ wol) {
  __shared__ float tile[64][68];
  const int blk = blockIdx.x, tid = threadIdx.x;
  if (blk < 1024) {
    size_t base = (size_t)blk * 4096 + (size_t)tid * 16;
#pragma unroll
    for (int p = 0; p < 2; p++) {
      size_t off = base + p * 8;
      float4 a = ldg4(&x[off]);
      float4 b2 = ldg4(&x[off + 4]);
      float v[8] = {a.x, a.y, a.z, a.w, b2.x, b2.y, b2.z, b2.w};
      ushort_t h[8], l[8];
#pragma unroll
      for (int j = 0; j < 8; j++) {
        h[j] = f2bf(v[j]);
        l[j] = f2bf(v[j] - bf2f(h[j]));
      }
      *(uint4*)&xh[off] = *(uint4*)&h[0];
      *(uint4*)&xl[off] = *(uint4*)&l[0];
    }
  } else if (blk < 1216) {
    // W transpose -> wt[1536][512] bf16
    int bi = blk - 1024;
    int g = bi / 64, t = bi % 64, tr = t >> 3, tc = t & 7;
    const float* Wg = (g == 0) ? Wq : (g == 1) ? Wk : Wv;
#pragma unroll
    for (int p = 0; p < 4; p++) {
      int u = tid + p * 256, r = u >> 4, c4 = (u & 15) * 4;
      *(float4*)&tile[r][c4] = ldg4(&Wg[(size_t)(tr * 64 + r) * CC + tc * 64 + c4]);
    }
    __syncthreads();
#pragma unroll
    for (int p = 0; p < 4; p++) {
      int u = tid + p * 256, n = u >> 4, k4 = (u & 15) * 4;
      ushort_t o[4];
#pragma unroll
      for (int i = 0; i < 4; i++) o[i] = f2bf(tile[k4 + i][n]);
      *(ushort4*)&wt[((size_t)g * 512 + tc * 64 + n) * 512 + tr * 64 + k4] =
          *(ushort4*)&o[0];
    }
  } else if (blk < 1280) {
    // Wo^T split bf16 -> woh/wol [512][512]
    int bi = blk - 1216;
    int tr = bi >> 3, tc = bi & 7;
#pragma unroll
    for (int p = 0; p < 4; p++) {
      int u = tid + p * 256, r = u >> 4, c4 = (u & 15) * 4;
      *(float4*)&tile[r][c4] = ldg4(&Wo[(size_t)(tr * 64 + r) * CC + tc * 64 + c4]);
    }
    __syncthreads();
#pragma unroll
    for (int p = 0; p < 4; p++) {
      int u = tid + p * 256, n = u >> 4, k4 = (u & 15) * 4;
      ushort_t oh[4], ol[4];
#pragma unroll
      for (int i = 0; i < 4; i++) {
        float v = tile[k4 + i][n];
        oh[i] = f2bf(v);
        ol[i] = f2bf(v - bf2f(oh[i]));
      }
      size_t dst = ((size_t)(tc * 64 + n)) * 512 + tr * 64 + k4;
      *(ushort4*)&woh[dst] = *(ushort4*)&oh[0];
      *(ushort4*)&wol[dst] = *(ushort4*)&ol[0];
    }
  } else if (blk < 1288) {
    // Erq/Erk bf16 convert
    int bi = blk - 1280;
#pragma unroll
    for (int it = 0; it < 16; it++) {
      int idx = bi * 16384 + it * 1024 + tid * 4;
      int g = idx >> 16, o = idx & 65535;
      const float* src = (g == 0) ? Erq : Erk;
      ushort_t* dst = (g == 0) ? erqb : erkb;
      float4 v = ldg4(&src[o]);
      ushort_t s[4] = {f2bf(v.x), f2bf(v.y), f2bf(v.z), f2bf(v.w)};
      *(ushort4*)&dst[o] = *(ushort4*)&s[0];
    }
  } else {
    // ervTpad[d][j] = Erv[j-1023][d] for j-1023 in [0,N), else 0
    int d = blk - 1288;  // 0..63
    for (int j = tid; j < EW3; j += 256) {
      ushort_t val = 0;
      int e = j - 1023;
      if (e >= 0 && e < NN) val = f2bf(Erv[e * 64 + d]);
      ervp[(size_t)d * EW3 + j] = val;
    }
  }
}

// ---------------- kernel 1: qkv = (xh+xl) @ W^T; v written transposed --------
__global__ __launch_bounds__(256) void proj_mfma(
    const ushort_t* __restrict__ xh, const ushort_t* __restrict__ xl,
    const ushort_t* __restrict__ wt, ushort_t* __restrict__ qkv) {
  __shared__ __align__(16) ushort_t Ah[128 * 40];
  __shared__ __align__(16) ushort_t Al[128 * 40];
  __shared__ __align__(16) ushort_t Bs[128 * 40];
  const int tid = threadIdx.x;
  const int w = tid >> 6, lane = tid & 63, l15 = lane & 15, quad = lane >> 4;
  const int q8 = quad * 8;
  const int m0 = blockIdx.x * 128, n0g = blockIdx.y * 128;
  const int mw = w & 1, nw = w >> 1;
  f32x4 acc[4][4] = {};
  for (int k0 = 0; k0 < CC; k0 += 32) {
    __syncthreads();
#pragma unroll
    for (int p = 0; p < 2; p++) {
      int u = tid + p * 256, row = u >> 2, q = (u & 3) * 8;
      *(uint4*)&Ah[row * 40 + q] = *(const uint4*)&xh[(size_t)(m0 + row) * CC + k0 + q];
      *(uint4*)&Al[row * 40 + q] = *(const uint4*)&xl[(size_t)(m0 + row) * CC + k0 + q];
      *(uint4*)&Bs[row * 40 + q] = *(const uint4*)&wt[(size_t)(n0g + row) * CC + k0 + q];
    }
    __syncthreads();
    bf16x8 ah[4], al[4];
#pragma unroll
    for (int mt = 0; mt < 4; mt++) {
      ah[mt] = *(const bf16x8*)&Ah[(mw * 64 + mt * 16 + l15) * 40 + q8];
      al[mt] = *(const bf16x8*)&Al[(mw * 64 + mt * 16 + l15) * 40 + q8];
    }
#pragma unroll
    for (int nt = 0; nt < 4; nt++) {
      bf16x8 bs = *(const bf16x8*)&Bs[(nw * 64 + nt * 16 + l15) * 40 + q8];
#pragma unroll
      for (int mt = 0; mt < 4; mt++) {
        acc[mt][nt] = MFMA(ah[mt], bs, acc[mt][nt]);
        acc[mt][nt] = MFMA(al[mt], bs, acc[mt][nt]);
      }
    }
  }
  const int g = n0g >> 9;
  if (g < 2) {
    ushort_t* outg = qkv + (size_t)g * PM * CC;
#pragma unroll
    for (int mt = 0; mt < 4; mt++) {
#pragma unroll
      for (int nt = 0; nt < 4; nt++) {
        int col = (n0g & 511) + nw * 64 + nt * 16 + l15;
#pragma unroll
        for (int r = 0; r < 4; r++) {
          int row = m0 + mw * 64 + mt * 16 + quad * 4 + r;
          outg[(size_t)row * CC + col] = f2bf(acc[mt][nt][r]);
        }
      }
    }
  } else {
    // v: write transposed vT[b][h][d][n]
    ushort_t* vT = qkv + (size_t)2 * PM * CC;
#pragma unroll
    for (int mt = 0; mt < 4; mt++) {
#pragma unroll
      for (int nt = 0; nt < 4; nt++) {
        int col = (n0g & 511) + nw * 64 + nt * 16 + l15;
        int hh = col >> 6, dd = col & 63;
        int row0 = m0 + mw * 64 + mt * 16 + quad * 4;
        int bI = row0 >> 10, nI = row0 & 1023;
        ushort_t pk4[4];
#pragma unroll
        for (int r = 0; r < 4; r++) pk4[r] = f2bf(acc[mt][nt][r]);
        *(ushort4*)&vT[(((size_t)(bI * HH + hh) * DD + dd) << 10) + nI] =
            *(ushort4*)&pk4[0];
      }
    }
  }
}

// ---------------- kernel 2: fused MFMA attention ----------------
__global__ __launch_bounds__(256, 4) void attn_kernel(
    const ushort_t* __restrict__ qb, const ushort_t* __restrict__ kb,
    const ushort_t* __restrict__ vT,
    const ushort_t* __restrict__ erq, const ushort_t* __restrict__ erk,
    const ushort_t* __restrict__ ervp,
    float* __restrict__ y, float* __restrict__ wz) {
  __shared__ uint_t Wwin[33 * 68];                   // packed {lq,lk}; stride 68
  __shared__ __align__(16) ushort_t Vt[2][64 * 40];  // v^T, double-buffered
  __shared__ __align__(16) ushort_t Psp[32 * 72];    // spread p
  __shared__ __align__(16) ushort_t Ptl[32 * 40];    // p normal
  __shared__ float Zp2[2][32];

  const int tid = threadIdx.x;
  const int w = tid >> 6, lane = tid & 63, l15 = lane & 15, quad = lane >> 4;
  const int q8 = quad * 8;
  const int bh = blockIdx.y, b = bh >> 3, h = bh & 7;
  const int r0 = blockIdx.x * 32;
  const size_t rowbase = (size_t)b * NN * CC + (size_t)h * DD;
  const size_t vbase = (size_t)bh << 16;

  for (int u = tid; u < 32 * 72 / 2; u += 256) ((uint_t*)Psp)[u] = 0;

  // QK roles: A = k rows (tt), B = q rows (ii, resident)
  const int ttW = w & 1, iiW = w >> 1;
  const int ii = iiW * 16 + l15;
  bf16x8 bq0 = *(const bf16x8*)&qb[rowbase + (size_t)(r0 + ii) * CC + q8];
  bf16x8 bq1 = *(const bf16x8*)&qb[rowbase + (size_t)(r0 + ii) * CC + 32 + q8];
  // roll roles
  const int term = w >> 1, ntR = w & 1;
  const ushort_t* asrc = term ? kb : qb;
  const ushort_t* erG = term ? erk : erq;
  ushort_t* WwU = (ushort_t*)Wwin;
  bf16x8 rA[3][2];
#pragma unroll
  for (int mt = 0; mt < 3; mt++) {
    int row = mt * 16 + l15, gr = r0 + row;
    bool ok = (row <= 32) && (gr < NN);
#pragma unroll
    for (int ks = 0; ks < 2; ks++) {
      bf16x8 zz = {};
      rA[mt][ks] = ok ? *(const bf16x8*)&asrc[rowbase + (size_t)gr * CC + ks * 32 + q8] : zz;
    }
  }

  auto load_rollB = [&](int u_base, bf16x8& b0, bf16x8& b1) {
    int s = ntR * 16 + l15;
    int p = u_base + s + NN - 1;
    int row = -1;
    if (p >= 0 && p <= NN - 1) row = p;
    else if (p >= NN + 1 && p <= 2 * NN - 2) row = p - NN - 1;
    bf16x8 zz = {};
    b0 = zz; b1 = zz;
    if (row >= 0) {
      b0 = *(const bf16x8*)&erG[row * 64 + q8];
      b1 = *(const bf16x8*)&erG[row * 64 + 32 + q8];
    }
  };
  auto do_roll = [&](int u_base, bf16x8 b0, bf16x8 b1) {
    int s = ntR * 16 + l15;
    int slot = (u_base + s) & 63;
#pragma unroll
    for (int mt = 0; mt < 3; mt++) {
      f32x4 c = {};
      c = MFMA(rA[mt][0], b0, c);
      c = MFMA(rA[mt][1], b1, c);
#pragma unroll
      for (int r = 0; r < 4; r++) {
        int wrow = mt * 16 + quad * 4 + r;
        if (wrow <= 32) WwU[(wrow * 68 + slot) * 2 + term] = f2bf(c[r]);
      }
    }
  };
  const int ed = tid >> 2, ec8 = (tid & 3) * 8;
  auto load_v = [&](int t0v, uint4& pv) {
    pv = *(const uint4*)&vT[vbase + ((size_t)ed << 10) + t0v + ec8];
  };
  auto stage_v = [&](int bufi, uint4 pv) {
    *(uint4*)&Vt[bufi][ed * 40 + ec8] = pv;
  };
  auto load_k = [&](int t0k, bf16x8& k0, bf16x8& k1) {
    const ushort_t* p = &kb[rowbase + (size_t)(t0k + ttW * 16 + l15) * CC];
    k0 = *(const bf16x8*)&p[q8];
    k1 = *(const bf16x8*)&p[32 + q8];
  };

  const int Mt = w & 1, nt0 = (w >> 1) * 2;
  const int tl0 = ttW * 16 + quad * 4;

  // ---- register-carried U/W B-fragment window (direct from L2-hot ervp) ----
  bf16x8 fu0[2], fu1[2], fw0[2], fw1[2];
#pragma unroll
  for (int t = 0; t < 2; t++) {
    const ushort_t* ep = &ervp[(size_t)((nt0 + t) * 16 + l15) * EW3 + r0 + q8];
    fu0[t] = *(const bf16x8*)&ep[0];
    fu1[t] = *(const bf16x8*)&ep[32];
    fw0[t] = *(const bf16x8*)&ep[NN];
    fw1[t] = *(const bf16x8*)&ep[NN + 32];
  }

  // init window + Vt[0]
  {
    bf16x8 b0, b1;
    load_rollB(-r0 - 32, b0, b1); do_roll(-r0 - 32, b0, b1);
    load_rollB(-r0, b0, b1);      do_roll(-r0, b0, b1);
    uint4 v0; load_v(0, v0); stage_v(0, v0);
  }
  bf16x8 pk0, pk1, pb0, pb1;
  uint4 pv;
  load_k(0, pk0, pk1);
  load_v(32, pv);
  load_rollB(32 - r0, pb0, pb1);

  f32x4 Sa[2] = {}, Ua[2] = {}, Wk_[2] = {};
  float zac = 0.f;

  for (int t0 = 0; t0 < NN; t0 += 32) {
    const int buf = (t0 >> 5) & 1;
    fast_barrier();  // B1: roll/staging(t-1) visible; P reads(t-1) done
    // ---- phase 2: QK MFMA + gather + exp + p writes ----
    {
      f32x4 cq = {};
      cq = MFMA(pk0, bq0, cq);
      cq = MFMA(pk1, bq1, cq);
      if (t0 + 32 < NN) load_k(t0 + 32, pk0, pk1);
      union { ushort_t pe[4]; uint2 u2; } P;
#pragma unroll
      for (int r = 0; r < 4; r++) {
        int u = (t0 + tl0 + r) - (r0 + ii);
        int isel = ii + (u >= 1 ? 1 : 0);
        uint_t w32 = Wwin[isel * 68 + (u & 63)];
        float lq = __uint_as_float(w32 << 16);
        float lk = __uint_as_float(w32 & 0xFFFF0000u);
        float e = __expf(fmaf(cq[r], 0.125f, lq + lk));
        zac += e;
        P.pe[r] = f2bf(e);
      }
      *(uint2*)&Ptl[ii * 40 + tl0] = P.u2;
      int pb = ii * 72 + ii + tl0;
      Psp[pb] = P.pe[0]; Psp[pb + 1] = P.pe[1];
      Psp[pb + 2] = P.pe[2]; Psp[pb + 3] = P.pe[3];
    }
    fast_barrier();  // B2: p visible; gather done
    // ---- phase 3: SUW MFMAs + V staging + window slide + roll ----
    {
      bf16x8 ap  = *(const bf16x8*)&Ptl[(Mt * 16 + l15) * 40 + q8];
      bf16x8 au0 = *(const bf16x8*)&Psp[(Mt * 16 + l15) * 72 + q8];
      bf16x8 au1 = *(const bf16x8*)&Psp[(Mt * 16 + l15) * 72 + 32 + q8];
#pragma unroll
      for (int t = 0; t < 2; t++) {
        bf16x8 bv = *(const bf16x8*)&Vt[buf][((nt0 + t) * 16 + l15) * 40 + q8];
        Sa[t] = MFMA(ap, bv, Sa[t]);
        Ua[t] = MFMA(au0, fu0[t], Ua[t]);
        Ua[t] = MFMA(au1, fu1[t], Ua[t]);
        Wk_[t] = MFMA(au0, fw0[t], Wk_[t]);
        Wk_[t] = MFMA(au1, fw1[t], Wk_[t]);
      }
      stage_v(buf ^ 1, pv);
      if (t0 + 64 < NN) load_v(t0 + 64, pv);
      // slide U/W register windows (fu0(t+32) = fu1(t)); prefetch next chunk
#pragma unroll
      for (int t = 0; t < 2; t++) {
        fu0[t] = fu1[t]; fw0[t] = fw1[t];
        const ushort_t* ep =
            &ervp[(size_t)((nt0 + t) * 16 + l15) * EW3 + r0 + t0 + 64 + q8];
        fu1[t] = *(const bf16x8*)&ep[0];
        fw1[t] = *(const bf16x8*)&ep[NN];
      }
      if (t0 + 32 < NN) {
        do_roll(t0 - r0 + 32, pb0, pb1);
        load_rollB(t0 - r0 + 64, pb0, pb1);
      }
    }
  }

  // ---- epilogue ----
  {
    float z = zac;
    z += __shfl_xor(z, 16);
    z += __shfl_xor(z, 32);
    if (lane < 16) Zp2[ttW][ii] = z;
  }
  __syncthreads();
#pragma unroll
  for (int t = 0; t < 2; t++) {
    int d = (nt0 + t) * 16 + l15;
#pragma unroll
    for (int r = 0; r < 4; r++) {
      int row = Mt * 16 + quad * 4 + r;
      float invz = 1.0f / (Zp2[0][row] + Zp2[1][row]);
      size_t off = rowbase + (size_t)(r0 + row) * CC + d;
      y[off] = (Sa[t][r] + Ua[t][r]) * invz;
      wz[off] = Wk_[t][r] * invz;
    }
  }
}

// ---------------- kernel 3: out = (y + shift(wz)) @ Wo + bo (split MFMA) ----
__global__ __launch_bounds__(256) void out_mfma(
    const float* __restrict__ y, const float* __restrict__ wz,
    const ushort_t* __restrict__ woh, const ushort_t* __restrict__ wol,
    const float* __restrict__ bo, float* __restrict__ out) {
  __shared__ __align__(16) ushort_t Ah[64 * 40];
  __shared__ __align__(16) ushort_t Al[64 * 40];
  __shared__ __align__(16) ushort_t Bh2[64 * 40];
  __shared__ __align__(16) ushort_t Bl2[64 * 40];
  const int tid = threadIdx.x;
  const int w = tid >> 6, lane = tid & 63, l15 = lane & 15, quad = lane >> 4;
  const int q8 = quad * 8;
  const int m0 = blockIdx.x * 64, n0 = blockIdx.y * 64;
  const int mw = w & 1, nw = w >> 1;
  const int row = tid >> 2, o8 = (tid & 3) * 8;
  f32x4 acc[2][2] = {};
  for (int k0 = 0; k0 < CC; k0 += 32) {
    __syncthreads();
    {
      int gm = m0 + row;
      const float* yp = &y[(size_t)gm * CC + k0 + o8];
      float4 a0 = ldg4(yp), a1 = ldg4(yp + 4);
      if ((gm & (NN - 1)) != NN - 1) {
        const float* wp = &wz[(size_t)(gm + 1) * CC + k0 + o8];
        float4 w0 = ldg4(wp), w1 = ldg4(wp + 4);
        a0.x += w0.x; a0.y += w0.y; a0.z += w0.z; a0.w += w0.w;
        a1.x += w1.x; a1.y += w1.y; a1.z += w1.z; a1.w += w1.w;
      }
      float vv[8] = {a0.x, a0.y, a0.z, a0.w, a1.x, a1.y, a1.z, a1.w};
      ushort_t hh[8], ll[8];
#pragma unroll
      for (int j = 0; j < 8; j++) {
        hh[j] = f2bf(vv[j]);
        ll[j] = f2bf(vv[j] - bf2f(hh[j]));
      }
      *(uint4*)&Ah[row * 40 + o8] = *(uint4*)&hh[0];
      *(uint4*)&Al[row * 40 + o8] = *(uint4*)&ll[0];
      size_t bsrc = (size_t)(n0 + row) * CC + k0 + o8;
      *(uint4*)&Bh2[row * 40 + o8] = *(const uint4*)&woh[bsrc];
      *(uint4*)&Bl2[row * 40 + o8] = *(const uint4*)&wol[bsrc];
    }
    __syncthreads();
    bf16x8 ah[2], al[2];
#pragma unroll
    for (int mt = 0; mt < 2; mt++) {
      ah[mt] = *(const bf16x8*)&Ah[(mw * 32 + mt * 16 + l15) * 40 + q8];
      al[mt] = *(const bf16x8*)&Al[(mw * 32 + mt * 16 + l15) * 40 + q8];
    }
#pragma unroll
    for (int nt = 0; nt < 2; nt++) {
      bf16x8 bh = *(const bf16x8*)&Bh2[(nw * 32 + nt * 16 + l15) * 40 + q8];
      bf16x8 bl = *(const bf16x8*)&Bl2[(nw * 32 + nt * 16 + l15) * 40 + q8];
#pragma unroll
      for (int mt = 0; mt < 2; mt++) {
        acc[mt][nt] = MFMA(ah[mt], bh, acc[mt][nt]);
        acc[mt][nt] = MFMA(al[mt], bh, acc[mt][nt]);
        acc[mt][nt] = MFMA(ah[mt], bl, acc[mt][nt]);
      }
    }
  }
#pragma unroll
  for (int mt = 0; mt < 2; mt++) {
#pragma unroll
    for (int nt = 0; nt < 2; nt++) {
      int col = n0 + nw * 32 + nt * 16 + l15;
      float bov = bo[col];
#pragma unroll
      for (int r = 0; r < 4; r++) {
        int rowo = m0 + mw * 32 + mt * 16 + quad * 4 + r;
        out[(size_t)rowo * CC + col] = acc[mt][nt][r] + bov;
      }
    }
  }
}

extern "C" void kernel_launch(void* const* d_in, const int* in_sizes, int n_in,
                              void* d_out, int out_size, void* d_ws, size_t ws_size,
                              hipStream_t stream) {
  const float* x   = (const float*)d_in[0];
  const float* Wq  = (const float*)d_in[1];
  const float* Wk  = (const float*)d_in[2];
  const float* Wv  = (const float*)d_in[3];
  const float* Erq = (const float*)d_in[4];
  const float* Erk = (const float*)d_in[5];
  const float* Erv = (const float*)d_in[6];
  const float* Wo  = (const float*)d_in[7];
  const float* bo  = (const float*)d_in[8];
  float* out = (float*)d_out;

  const size_t M = (size_t)PM * CC;  // 4,194,304
  ushort_t* qb   = (ushort_t*)d_ws;  // [q][k][vT] contiguous
  ushort_t* kb   = qb + M;
  ushort_t* vTb  = kb + M;
  ushort_t* erqb = vTb + M;
  ushort_t* erkb = erqb + NN * DD;
  ushort_t* ervp = erkb + NN * DD;        // 64*3200
  ushort_t* wohb = ervp + (size_t)DD * EW3;
  ushort_t* wolb = wohb + (size_t)CC * CC;
  ushort_t* wtb  = wolb + (size_t)CC * CC;  // 1536*512
  ushort_t* xhb  = wtb + (size_t)1536 * 512;
  ushort_t* xlb  = xhb + M;
  float* yb  = (float*)(xlb + M);
  float* wzb = yb + M;

  prep_kernel<<<1352, 256, 0, stream>>>(x, Wq, Wk, Wv, Erq, Erk, Erv, Wo,
                                        xhb, xlb, wtb, erqb, erkb, ervp,
                                        wohb, wolb);
  proj_mfma<<<dim3(64, 12), 256, 0, stream>>>(xhb, xlb, wtb, qb);
  attn_kernel<<<dim3(32, 64), 256, 0, stream>>>(qb, kb, vTb, erqb, erkb, ervp,
                                                yb, wzb);
  out_mfma<<<dim3(128, 8), 256, 0, stream>>>(yb, wzb, wohb, wolb, bo, out);
}

// Round 8
// 321.163 us; speedup vs baseline: 2.0149x; 2.0149x over previous
//
#include <hip/hip_runtime.h>
#include <hip/hip_bf16.h>
#include <cstddef>

// AxialAttention (Music-Transformer skew trick), MFMA bf16, pipelined v6.
// B=8, N=1024, C=512, H=8, d=64.
// logits[r,t] = scale*q[r].k[t] + q[rsel].Erq'[p] + k[rsel].Erk'[p]
//   u=t-r, p=u+N-1, rsel=r+(u>=1)
// S[r]=sum p v; U[r]=sum p Erv[m+r-(N-1)]; W[r]=sum p Erv[m+r+1]
// y[r]=(S+U)/Z; wz[r]=W/Z; out = (y + rowshift(wz)) @ Wo + bo
// MFMA 16x16x32 bf16: A[m=lane&15][k=quad*8+j], B[n=lane&15][k=quad*8+j],
// C/D col=lane&15, row=quad*4+reg.
//
// v6 = R4 structure (LDS rings; proven fastest) + register-slide of ring
// B-fragments: ring slot sl0(t0+32)==sl1(t0) and contents are stable for 2
// iterations, so fu0/fw0 carry over in registers and only bu1/bw1 are read
// from LDS each iter (-16 of 52 b128 reads per block-iter).
// HARD LESSON (R5, R7): multiply-read B-fragments MUST stage through LDS;
// direct global fragment reads explode FETCH_SIZE (75MB -> 1GB) because
// streaming q/k/vT evicts even a 400KB table from per-XCD L2.

#define BB 8
#define NN 1024
#define CC 512
#define HH 8
#define DD 64
#define PM 8192
#define EW3 3200  // ervTpad width

typedef unsigned short ushort_t;
typedef unsigned int uint_t;
typedef __bf16 bf16x8 __attribute__((ext_vector_type(8)));
typedef float f32x4 __attribute__((ext_vector_type(4)));
#define MFMA(a, b, c) __builtin_amdgcn_mfma_f32_16x16x32_bf16(a, b, c, 0, 0, 0)

// Barrier draining only LDS ops (register-destined global loads stay in
// flight). All cross-thread data flows through LDS -> lgkmcnt(0) suffices.
__device__ __forceinline__ void fast_barrier() {
  asm volatile("s_waitcnt lgkmcnt(0)\n\ts_barrier" ::: "memory");
}

__device__ __forceinline__ ushort_t f2bf(float f) {
  union { float f; uint_t u; } v; v.f = f;
  uint_t r = v.u + 0x7FFFu + ((v.u >> 16) & 1u);
  return (ushort_t)(r >> 16);
}
__device__ __forceinline__ float bf2f(ushort_t u) {
  union { uint_t u; float f; } v; v.u = ((uint_t)u) << 16; return v.f;
}
__device__ __forceinline__ float4 ldg4(const float* p) { return *(const float4*)p; }

// ---------------- prep ----------------
__global__ __launch_bounds__(256) void prep_kernel(
    const float* __restrict__ x, const float* __restrict__ Wq,
    const float* __restrict__ Wk, const float* __restrict__ Wv,
    const float* __restrict__ Erq, const float* __restrict__ Erk,
    const float* __restrict__ Erv, const float* __restrict__ Wo,
    ushort_t* __restrict__ xh, ushort_t* __restrict__ xl,
    ushort_t* __restrict__ wt, ushort_t* __restrict__ erqb,
    ushort_t* __restrict__ erkb, ushort_t* __restrict__ ervp,
    ushort_t* __restrict__ woh, ushort_t* __restrict__ wol) {
  __shared__ float tile[64][68];
  const int blk = blockIdx.x, tid = threadIdx.x;
  if (blk < 1024) {
    size_t base = (size_t)blk * 4096 + (size_t)tid * 16;
#pragma unroll
    for (int p = 0; p < 2; p++) {
      size_t off = base + p * 8;
      float4 a = ldg4(&x[off]);
      float4 b2 = ldg4(&x[off + 4]);
      float v[8] = {a.x, a.y, a.z, a.w, b2.x, b2.y, b2.z, b2.w};
      ushort_t h[8], l[8];
#pragma unroll
      for (int j = 0; j < 8; j++) {
        h[j] = f2bf(v[j]);
        l[j] = f2bf(v[j] - bf2f(h[j]));
      }
      *(uint4*)&xh[off] = *(uint4*)&h[0];
      *(uint4*)&xl[off] = *(uint4*)&l[0];
    }
  } else if (blk < 1216) {
    // W transpose -> wt[1536][512] bf16
    int bi = blk - 1024;
    int g = bi / 64, t = bi % 64, tr = t >> 3, tc = t & 7;
    const float* Wg = (g == 0) ? Wq : (g == 1) ? Wk : Wv;
#pragma unroll
    for (int p = 0; p < 4; p++) {
      int u = tid + p * 256, r = u >> 4, c4 = (u & 15) * 4;
      *(float4*)&tile[r][c4] = ldg4(&Wg[(size_t)(tr * 64 + r) * CC + tc * 64 + c4]);
    }
    __syncthreads();
#pragma unroll
    for (int p = 0; p < 4; p++) {
      int u = tid + p * 256, n = u >> 4, k4 = (u & 15) * 4;
      ushort_t o[4];
#pragma unroll
      for (int i = 0; i < 4; i++) o[i] = f2bf(tile[k4 + i][n]);
      *(ushort4*)&wt[((size_t)g * 512 + tc * 64 + n) * 512 + tr * 64 + k4] =
          *(ushort4*)&o[0];
    }
  } else if (blk < 1280) {
    // Wo^T split bf16 -> woh/wol [512][512]
    int bi = blk - 1216;
    int tr = bi >> 3, tc = bi & 7;
#pragma unroll
    for (int p = 0; p < 4; p++) {
      int u = tid + p * 256, r = u >> 4, c4 = (u & 15) * 4;
      *(float4*)&tile[r][c4] = ldg4(&Wo[(size_t)(tr * 64 + r) * CC + tc * 64 + c4]);
    }
    __syncthreads();
#pragma unroll
    for (int p = 0; p < 4; p++) {
      int u = tid + p * 256, n = u >> 4, k4 = (u & 15) * 4;
      ushort_t oh[4], ol[4];
#pragma unroll
      for (int i = 0; i < 4; i++) {
        float v = tile[k4 + i][n];
        oh[i] = f2bf(v);
        ol[i] = f2bf(v - bf2f(oh[i]));
      }
      size_t dst = ((size_t)(tc * 64 + n)) * 512 + tr * 64 + k4;
      *(ushort4*)&woh[dst] = *(ushort4*)&oh[0];
      *(ushort4*)&wol[dst] = *(ushort4*)&ol[0];
    }
  } else if (blk < 1288) {
    // Erq/Erk bf16 convert
    int bi = blk - 1280;
#pragma unroll
    for (int it = 0; it < 16; it++) {
      int idx = bi * 16384 + it * 1024 + tid * 4;
      int g = idx >> 16, o = idx & 65535;
      const float* src = (g == 0) ? Erq : Erk;
      ushort_t* dst = (g == 0) ? erqb : erkb;
      float4 v = ldg4(&src[o]);
      ushort_t s[4] = {f2bf(v.x), f2bf(v.y), f2bf(v.z), f2bf(v.w)};
      *(ushort4*)&dst[o] = *(ushort4*)&s[0];
    }
  } else {
    // ervTpad[d][j] = Erv[j-1023][d] for j-1023 in [0,N), else 0
    int d = blk - 1288;  // 0..63
    for (int j = tid; j < EW3; j += 256) {
      ushort_t val = 0;
      int e = j - 1023;
      if (e >= 0 && e < NN) val = f2bf(Erv[e * 64 + d]);
      ervp[(size_t)d * EW3 + j] = val;
    }
  }
}

// ---------------- kernel 1: qkv = (xh+xl) @ W^T; v written transposed --------
__global__ __launch_bounds__(256) void proj_mfma(
    const ushort_t* __restrict__ xh, const ushort_t* __restrict__ xl,
    const ushort_t* __restrict__ wt, ushort_t* __restrict__ qkv) {
  __shared__ __align__(16) ushort_t Ah[128 * 40];
  __shared__ __align__(16) ushort_t Al[128 * 40];
  __shared__ __align__(16) ushort_t Bs[128 * 40];
  const int tid = threadIdx.x;
  const int w = tid >> 6, lane = tid & 63, l15 = lane & 15, quad = lane >> 4;
  const int q8 = quad * 8;
  const int m0 = blockIdx.x * 128, n0g = blockIdx.y * 128;
  const int mw = w & 1, nw = w >> 1;
  f32x4 acc[4][4] = {};
  for (int k0 = 0; k0 < CC; k0 += 32) {
    __syncthreads();
#pragma unroll
    for (int p = 0; p < 2; p++) {
      int u = tid + p * 256, row = u >> 2, q = (u & 3) * 8;
      *(uint4*)&Ah[row * 40 + q] = *(const uint4*)&xh[(size_t)(m0 + row) * CC + k0 + q];
      *(uint4*)&Al[row * 40 + q] = *(const uint4*)&xl[(size_t)(m0 + row) * CC + k0 + q];
      *(uint4*)&Bs[row * 40 + q] = *(const uint4*)&wt[(size_t)(n0g + row) * CC + k0 + q];
    }
    __syncthreads();
    bf16x8 ah[4], al[4];
#pragma unroll
    for (int mt = 0; mt < 4; mt++) {
      ah[mt] = *(const bf16x8*)&Ah[(mw * 64 + mt * 16 + l15) * 40 + q8];
      al[mt] = *(const bf16x8*)&Al[(mw * 64 + mt * 16 + l15) * 40 + q8];
    }
#pragma unroll
    for (int nt = 0; nt < 4; nt++) {
      bf16x8 bs = *(const bf16x8*)&Bs[(nw * 64 + nt * 16 + l15) * 40 + q8];
#pragma unroll
      for (int mt = 0; mt < 4; mt++) {
        acc[mt][nt] = MFMA(ah[mt], bs, acc[mt][nt]);
        acc[mt][nt] = MFMA(al[mt], bs, acc[mt][nt]);
      }
    }
  }
  const int g = n0g >> 9;
  if (g < 2) {
    ushort_t* outg = qkv + (size_t)g * PM * CC;
#pragma unroll
    for (int mt = 0; mt < 4; mt++) {
#pragma unroll
      for (int nt = 0; nt < 4; nt++) {
        int col = (n0g & 511) + nw * 64 + nt * 16 + l15;
#pragma unroll
        for (int r = 0; r < 4; r++) {
          int row = m0 + mw * 64 + mt * 16 + quad * 4 + r;
          outg[(size_t)row * CC + col] = f2bf(acc[mt][nt][r]);
        }
      }
    }
  } else {
    // v: write transposed vT[b][h][d][n]
    ushort_t* vT = qkv + (size_t)2 * PM * CC;
#pragma unroll
    for (int mt = 0; mt < 4; mt++) {
#pragma unroll
      for (int nt = 0; nt < 4; nt++) {
        int col = (n0g & 511) + nw * 64 + nt * 16 + l15;
        int hh = col >> 6, dd = col & 63;
        int row0 = m0 + mw * 64 + mt * 16 + quad * 4;
        int bI = row0 >> 10, nI = row0 & 1023;
        ushort_t pk4[4];
#pragma unroll
        for (int r = 0; r < 4; r++) pk4[r] = f2bf(acc[mt][nt][r]);
        *(ushort4*)&vT[(((size_t)(bI * HH + hh) * DD + dd) << 10) + nI] =
            *(ushort4*)&pk4[0];
      }
    }
  }
}

// ---------------- kernel 2: fused MFMA attention ----------------
__global__ __launch_bounds__(256, 3) void attn_kernel(
    const ushort_t* __restrict__ qb, const ushort_t* __restrict__ kb,
    const ushort_t* __restrict__ vT,
    const ushort_t* __restrict__ erq, const ushort_t* __restrict__ erk,
    const ushort_t* __restrict__ ervp,
    float* __restrict__ y, float* __restrict__ wz) {
  __shared__ uint_t Wwin[33 * 68];                   // packed {lq,lk}; stride 68
  __shared__ __align__(16) ushort_t Vt[2][64 * 40];  // v^T, double-buffered
  __shared__ __align__(16) ushort_t EUt[64 * 104];   // ErvU band^T 96-ring
  __shared__ __align__(16) ushort_t EWt[64 * 104];   // ErvW band^T 96-ring
  __shared__ __align__(16) ushort_t Psp[32 * 72];    // spread p
  __shared__ __align__(16) ushort_t Ptl[32 * 40];    // p normal
  __shared__ float Zp2[2][32];

  const int tid = threadIdx.x;
  const int w = tid >> 6, lane = tid & 63, l15 = lane & 15, quad = lane >> 4;
  const int q8 = quad * 8;
  const int bh = blockIdx.y, b = bh >> 3, h = bh & 7;
  const int r0 = blockIdx.x * 32;
  const size_t rowbase = (size_t)b * NN * CC + (size_t)h * DD;
  const size_t vbase = (size_t)bh << 16;

  for (int u = tid; u < 32 * 72 / 2; u += 256) ((uint_t*)Psp)[u] = 0;

  // QK roles: A = k rows (tt), B = q rows (ii, resident)
  const int ttW = w & 1, iiW = w >> 1;
  const int ii = iiW * 16 + l15;
  bf16x8 bq0 = *(const bf16x8*)&qb[rowbase + (size_t)(r0 + ii) * CC + q8];
  bf16x8 bq1 = *(const bf16x8*)&qb[rowbase + (size_t)(r0 + ii) * CC + 32 + q8];
  // roll roles
  const int term = w >> 1, ntR = w & 1;
  const ushort_t* asrc = term ? kb : qb;
  const ushort_t* erG = term ? erk : erq;
  ushort_t* WwU = (ushort_t*)Wwin;
  bf16x8 rA[3][2];
#pragma unroll
  for (int mt = 0; mt < 3; mt++) {
    int row = mt * 16 + l15, gr = r0 + row;
    bool ok = (row <= 32) && (gr < NN);
#pragma unroll
    for (int ks = 0; ks < 2; ks++) {
      bf16x8 zz = {};
      rA[mt][ks] = ok ? *(const bf16x8*)&asrc[rowbase + (size_t)gr * CC + ks * 32 + q8] : zz;
    }
  }

  auto load_rollB = [&](int u_base, bf16x8& b0, bf16x8& b1) {
    int s = ntR * 16 + l15;
    int p = u_base + s + NN - 1;
    int row = -1;
    if (p >= 0 && p <= NN - 1) row = p;
    else if (p >= NN + 1 && p <= 2 * NN - 2) row = p - NN - 1;
    bf16x8 zz = {};
    b0 = zz; b1 = zz;
    if (row >= 0) {
      b0 = *(const bf16x8*)&erG[row * 64 + q8];
      b1 = *(const bf16x8*)&erG[row * 64 + 32 + q8];
    }
  };
  auto do_roll = [&](int u_base, bf16x8 b0, bf16x8 b1) {
    int s = ntR * 16 + l15;
    int slot = (u_base + s) & 63;
#pragma unroll
    for (int mt = 0; mt < 3; mt++) {
      f32x4 c = {};
      c = MFMA(rA[mt][0], b0, c);
      c = MFMA(rA[mt][1], b1, c);
#pragma unroll
      for (int r = 0; r < 4; r++) {
        int wrow = mt * 16 + quad * 4 + r;
        if (wrow <= 32) WwU[(wrow * 68 + slot) * 2 + term] = f2bf(c[r]);
      }
    }
  };
  const int ed = tid >> 2, ec8 = (tid & 3) * 8;
  auto load_erv = [&](int eoff0, uint4& pu, uint4& pw) {
    size_t idx = (size_t)ed * EW3 + r0 + eoff0 + ec8;
    pu = *(const uint4*)&ervp[idx];
    pw = *(const uint4*)&ervp[idx + NN];
  };
  auto stage_erv = [&](int eoff0, uint4 pu, uint4 pw) {
    int slot = (eoff0 % 96) + ec8;
    *(uint4*)&EUt[ed * 104 + slot] = pu;
    *(uint4*)&EWt[ed * 104 + slot] = pw;
  };
  auto load_v = [&](int t0v, uint4& pv) {
    pv = *(const uint4*)&vT[vbase + ((size_t)ed << 10) + t0v + ec8];
  };
  auto stage_v = [&](int bufi, uint4 pv) {
    *(uint4*)&Vt[bufi][ed * 40 + ec8] = pv;
  };
  auto load_k = [&](int t0k, bf16x8& k0, bf16x8& k1) {
    const ushort_t* p = &kb[rowbase + (size_t)(t0k + ttW * 16 + l15) * CC];
    k0 = *(const bf16x8*)&p[q8];
    k1 = *(const bf16x8*)&p[32 + q8];
  };

  const int Mt = w & 1, nt0 = (w >> 1) * 2;
  const int tl0 = ttW * 16 + quad * 4;

  // init: windows, ring chunks 0/32, Vt[0]
  {
    bf16x8 b0, b1;
    load_rollB(-r0 - 32, b0, b1); do_roll(-r0 - 32, b0, b1);
    load_rollB(-r0, b0, b1);      do_roll(-r0, b0, b1);
    uint4 pu0, pw0;
    load_erv(0, pu0, pw0);  stage_erv(0, pu0, pw0);
    load_erv(32, pu0, pw0); stage_erv(32, pu0, pw0);
    uint4 v0; load_v(0, v0); stage_v(0, v0);
  }
  fast_barrier();  // ring chunks 0/32 visible for priming reads

  // prime the sliding ring B-fragments (slot q8 == sl0 at t0=0)
  bf16x8 fu0[2], fw0[2];
#pragma unroll
  for (int t = 0; t < 2; t++) {
    int drow = (nt0 + t) * 16 + l15;
    fu0[t] = *(const bf16x8*)&EUt[drow * 104 + q8];
    fw0[t] = *(const bf16x8*)&EWt[drow * 104 + q8];
  }

  bf16x8 pk0, pk1, pb0, pb1;
  uint4 pv, pu, pw;
  load_k(0, pk0, pk1);
  load_v(32, pv);
  load_erv(64, pu, pw);
  load_rollB(32 - r0, pb0, pb1);

  f32x4 Sa[2] = {}, Ua[2] = {}, Wk_[2] = {};
  float zac = 0.f;

  for (int t0 = 0; t0 < NN; t0 += 32) {
    const int buf = (t0 >> 5) & 1;
    fast_barrier();  // B1: roll/staging(t-1) visible; P reads(t-1) done
    // ---- phase 2: QK MFMA + gather + exp + p writes ----
    {
      f32x4 cq = {};
      cq = MFMA(pk0, bq0, cq);
      cq = MFMA(pk1, bq1, cq);
      if (t0 + 32 < NN) load_k(t0 + 32, pk0, pk1);
      union { ushort_t pe[4]; uint2 u2; } P;
#pragma unroll
      for (int r = 0; r < 4; r++) {
        int u = (t0 + tl0 + r) - (r0 + ii);
        int isel = ii + (u >= 1 ? 1 : 0);
        uint_t w32 = Wwin[isel * 68 + (u & 63)];
        float lq = __uint_as_float(w32 << 16);
        float lk = __uint_as_float(w32 & 0xFFFF0000u);
        float e = __expf(fmaf(cq[r], 0.125f, lq + lk));
        zac += e;
        P.pe[r] = f2bf(e);
      }
      *(uint2*)&Ptl[ii * 40 + tl0] = P.u2;
      int pb = ii * 72 + ii + tl0;
      Psp[pb] = P.pe[0]; Psp[pb + 1] = P.pe[1];
      Psp[pb + 2] = P.pe[2]; Psp[pb + 3] = P.pe[3];
    }
    fast_barrier();  // B2: p visible; gather done
    // ---- phase 3: SUW MFMAs (slide rings) + staging + roll ----
    {
      bf16x8 ap  = *(const bf16x8*)&Ptl[(Mt * 16 + l15) * 40 + q8];
      bf16x8 au0 = *(const bf16x8*)&Psp[(Mt * 16 + l15) * 72 + q8];
      bf16x8 au1 = *(const bf16x8*)&Psp[(Mt * 16 + l15) * 72 + 32 + q8];
      int sl1 = (t0 + 32 + q8) % 96;
#pragma unroll
      for (int t = 0; t < 2; t++) {
        int drow = (nt0 + t) * 16 + l15;
        bf16x8 bv = *(const bf16x8*)&Vt[buf][drow * 40 + q8];
        Sa[t] = MFMA(ap, bv, Sa[t]);
        bf16x8 bu1 = *(const bf16x8*)&EUt[drow * 104 + sl1];
        bf16x8 bw1 = *(const bf16x8*)&EWt[drow * 104 + sl1];
        Ua[t] = MFMA(au0, fu0[t], Ua[t]);
        Ua[t] = MFMA(au1, bu1, Ua[t]);
        Wk_[t] = MFMA(au0, fw0[t], Wk_[t]);
        Wk_[t] = MFMA(au1, bw1, Wk_[t]);
        fu0[t] = bu1;  // slot sl1(t0) == sl0(t0+32), contents stable 2 iters
        fw0[t] = bw1;
      }
      stage_v(buf ^ 1, pv);
      if (t0 + 64 < NN) load_v(t0 + 64, pv);
      stage_erv(t0 + 64, pu, pw);
      load_erv(t0 + 96, pu, pw);
      if (t0 + 32 < NN) {
        do_roll(t0 - r0 + 32, pb0, pb1);
        load_rollB(t0 - r0 + 64, pb0, pb1);
      }
    }
  }

  // ---- epilogue ----
  {
    float z = zac;
    z += __shfl_xor(z, 16);
    z += __shfl_xor(z, 32);
    if (lane < 16) Zp2[ttW][ii] = z;
  }
  __syncthreads();
#pragma unroll
  for (int t = 0; t < 2; t++) {
    int d = (nt0 + t) * 16 + l15;
#pragma unroll
    for (int r = 0; r < 4; r++) {
      int row = Mt * 16 + quad * 4 + r;
      float invz = 1.0f / (Zp2[0][row] + Zp2[1][row]);
      size_t off = rowbase + (size_t)(r0 + row) * CC + d;
      y[off] = (Sa[t][r] + Ua[t][r]) * invz;
      wz[off] = Wk_[t][r] * invz;
    }
  }
}

// ---------------- kernel 3: out = (y + shift(wz)) @ Wo + bo (split MFMA) ----
__global__ __launch_bounds__(256) void out_mfma(
    const float* __restrict__ y, const float* __restrict__ wz,
    const ushort_t* __restrict__ woh, const ushort_t* __restrict__ wol,
    const float* __restrict__ bo, float* __restrict__ out) {
  __shared__ __align__(16) ushort_t Ah[64 * 40];
  __shared__ __align__(16) ushort_t Al[64 * 40];
  __shared__ __align__(16) ushort_t Bh2[64 * 40];
  __shared__ __align__(16) ushort_t Bl2[64 * 40];
  const int tid = threadIdx.x;
  const int w = tid >> 6, lane = tid & 63, l15 = lane & 15, quad = lane >> 4;
  const int q8 = quad * 8;
  const int m0 = blockIdx.x * 64, n0 = blockIdx.y * 64;
  const int mw = w & 1, nw = w >> 1;
  const int row = tid >> 2, o8 = (tid & 3) * 8;
  f32x4 acc[2][2] = {};
  for (int k0 = 0; k0 < CC; k0 += 32) {
    __syncthreads();
    {
      int gm = m0 + row;
      const float* yp = &y[(size_t)gm * CC + k0 + o8];
      float4 a0 = ldg4(yp), a1 = ldg4(yp + 4);
      if ((gm & (NN - 1)) != NN - 1) {
        const float* wp = &wz[(size_t)(gm + 1) * CC + k0 + o8];
        float4 w0 = ldg4(wp), w1 = ldg4(wp + 4);
        a0.x += w0.x; a0.y += w0.y; a0.z += w0.z; a0.w += w0.w;
        a1.x += w1.x; a1.y += w1.y; a1.z += w1.z; a1.w += w1.w;
      }
      float vv[8] = {a0.x, a0.y, a0.z, a0.w, a1.x, a1.y, a1.z, a1.w};
      ushort_t hh[8], ll[8];
#pragma unroll
      for (int j = 0; j < 8; j++) {
        hh[j] = f2bf(vv[j]);
        ll[j] = f2bf(vv[j] - bf2f(hh[j]));
      }
      *(uint4*)&Ah[row * 40 + o8] = *(uint4*)&hh[0];
      *(uint4*)&Al[row * 40 + o8] = *(uint4*)&ll[0];
      size_t bsrc = (size_t)(n0 + row) * CC + k0 + o8;
      *(uint4*)&Bh2[row * 40 + o8] = *(const uint4*)&woh[bsrc];
      *(uint4*)&Bl2[row * 40 + o8] = *(const uint4*)&wol[bsrc];
    }
    __syncthreads();
    bf16x8 ah[2], al[2];
#pragma unroll
    for (int mt = 0; mt < 2; mt++) {
      ah[mt] = *(const bf16x8*)&Ah[(mw * 32 + mt * 16 + l15) * 40 + q8];
      al[mt] = *(const bf16x8*)&Al[(mw * 32 + mt * 16 + l15) * 40 + q8];
    }
#pragma unroll
    for (int nt = 0; nt < 2; nt++) {
      bf16x8 bh = *(const bf16x8*)&Bh2[(nw * 32 + nt * 16 + l15) * 40 + q8];
      bf16x8 bl = *(const bf16x8*)&Bl2[(nw * 32 + nt * 16 + l15) * 40 + q8];
#pragma unroll
      for (int mt = 0; mt < 2; mt++) {
        acc[mt][nt] = MFMA(ah[mt], bh, acc[mt][nt]);
        acc[mt][nt] = MFMA(al[mt], bh, acc[mt][nt]);
        acc[mt][nt] = MFMA(ah[mt], bl, acc[mt][nt]);
      }
    }
  }
#pragma unroll
  for (int mt = 0; mt < 2; mt++) {
#pragma unroll
    for (int nt = 0; nt < 2; nt++) {
      int col = n0 + nw * 32 + nt * 16 + l15;
      float bov = bo[col];
#pragma unroll
      for (int r = 0; r < 4; r++) {
        int rowo = m0 + mw * 32 + mt * 16 + quad * 4 + r;
        out[(size_t)rowo * CC + col] = acc[mt][nt][r] + bov;
      }
    }
  }
}

extern "C" void kernel_launch(void* const* d_in, const int* in_sizes, int n_in,
                              void* d_out, int out_size, void* d_ws, size_t ws_size,
                              hipStream_t stream) {
  const float* x   = (const float*)d_in[0];
  const float* Wq  = (const float*)d_in[1];
  const float* Wk  = (const float*)d_in[2];
  const float* Wv  = (const float*)d_in[3];
  const float* Erq = (const float*)d_in[4];
  const float* Erk = (const float*)d_in[5];
  const float* Erv = (const float*)d_in[6];
  const float* Wo  = (const float*)d_in[7];
  const float* bo  = (const float*)d_in[8];
  float* out = (float*)d_out;

  const size_t M = (size_t)PM * CC;  // 4,194,304
  ushort_t* qb   = (ushort_t*)d_ws;  // [q][k][vT] contiguous
  ushort_t* kb   = qb + M;
  ushort_t* vTb  = kb + M;
  ushort_t* erqb = vTb + M;
  ushort_t* erkb = erqb + NN * DD;
  ushort_t* ervp = erkb + NN * DD;        // 64*3200
  ushort_t* wohb = ervp + (size_t)DD * EW3;
  ushort_t* wolb = wohb + (size_t)CC * CC;
  ushort_t* wtb  = wolb + (size_t)CC * CC;  // 1536*512
  ushort_t* xhb  = wtb + (size_t)1536 * 512;
  ushort_t* xlb  = xhb + M;
  float* yb  = (float*)(xlb + M);
  float* wzb = yb + M;

  prep_kernel<<<1352, 256, 0, stream>>>(x, Wq, Wk, Wv, Erq, Erk, Erv, Wo,
                                        xhb, xlb, wtb, erqb, erkb, ervp,
                                        wohb, wolb);
  proj_mfma<<<dim3(64, 12), 256, 0, stream>>>(xhb, xlb, wtb, qb);
  attn_kernel<<<dim3(32, 64), 256, 0, stream>>>(qb, kb, vTb, erqb, erkb, ervp,
                                                yb, wzb);
  out_mfma<<<dim3(128, 8), 256, 0, stream>>>(yb, wzb, wohb, wolb, bo, out);
}